// Round 7
// baseline (249.301 us; speedup 1.0000x reference)
//
#include <hip/hip_runtime.h>

// ---------------------------------------------------------------------------
// Head_87033217286245 — Round 7. Same algebraic structure as R6 (conv GEMM is
// never materialized), with the post-dots pipeline restructured:
//  * Wt2[t][k][o] / fcT[i][j] transposed operands -> coalesced consumer reads
//    (R6's head did 64-line-scatter per load inst: the hidden ~60-90us).
//  * coef_kernel precomputes per-row span/tap exp-weights C[b][m][12] + Z.
//  * span_acc: grid (b x 8 row-octants), each row of X read ONCE for all
//    3 spans x 3 taps (union traffic, static balance), ballot-compacted rows.
// ---------------------------------------------------------------------------

typedef float f32x4 __attribute__((ext_vector_type(4)));

#define B_      128
#define L_      512
#define NSPANS  3
#define HIDDEN  512

__device__ __forceinline__ float dp4(f32x4 a, f32x4 b) {
    return a.x*b.x + a.y*b.y + a.z*b.z + a.w*b.w;
}

// ---- k0: u_t[k] = Sum_o W[o,k,t]*aw[o];  Wt2[t][k][o];  fcT[i][j]
__global__ __launch_bounds__(256)
void prep_kernel(const float* __restrict__ cw, const float* __restrict__ aw,
                 const float* __restrict__ fcw,
                 float* __restrict__ u, float* __restrict__ Wt2,
                 float* __restrict__ fcT) {
    const int idx = blockIdx.x * 256 + threadIdx.x;      // 96*256 = 24576
    if (idx < 3072) {
        const int t = idx >> 10, k = idx & 1023;
        float s = 0.f;
        #pragma unroll 8
        for (int o = 0; o < 64; ++o)
            s += cw[(size_t)(o * 1024 + k) * 3 + t] * aw[o];
        u[idx] = s;
    }
    for (int i = idx; i < 196608; i += 24576) {          // Wt2[(t*1024+k)*64+o]
        const int o = i & 63, k = (i >> 6) & 1023, t = i >> 16;
        Wt2[i] = cw[(size_t)(o * 1024 + k) * 3 + t];
    }
    for (int i = idx; i < 98304; i += 24576) {           // fcT[r*512+j] = fcw[j*192+r]
        const int j = i & 511, r = i >> 9;
        fcT[i] = fcw[(size_t)j * 192 + r];
    }
}

// ---- k1: d_t[m] = X[m,:]·u_t  (unchanged from R6 — verified)
__global__ __launch_bounds__(256, 4)
void dots_kernel(const float* __restrict__ X, const float* __restrict__ u,
                 float* __restrict__ d0, float* __restrict__ d1,
                 float* __restrict__ d2) {
    const int tid = threadIdx.x, lane = tid & 63, wv = tid >> 6;
    f32x4 uu[3][4];
    #pragma unroll
    for (int t = 0; t < 3; ++t)
        #pragma unroll
        for (int q = 0; q < 4; ++q)
            uu[t][q] = *(const f32x4*)(u + t * 1024 + q * 256 + lane * 4);

    const int wrow0 = (blockIdx.x * 4 + wv) * 8;         // 2048 blocks
    const float* xp = X + (size_t)wrow0 * 1024 + lane * 4;
    #pragma unroll 2
    for (int i = 0; i < 8; ++i) {
        const float* rp = xp + (size_t)i * 1024;
        f32x4 x0 = *(const f32x4*)(rp);
        f32x4 x1 = *(const f32x4*)(rp + 256);
        f32x4 x2 = *(const f32x4*)(rp + 512);
        f32x4 x3 = *(const f32x4*)(rp + 768);
        float p0 = dp4(x0, uu[0][0]) + dp4(x1, uu[0][1]) + dp4(x2, uu[0][2]) + dp4(x3, uu[0][3]);
        float p1 = dp4(x0, uu[1][0]) + dp4(x1, uu[1][1]) + dp4(x2, uu[1][2]) + dp4(x3, uu[1][3]);
        float p2 = dp4(x0, uu[2][0]) + dp4(x1, uu[2][1]) + dp4(x2, uu[2][2]) + dp4(x3, uu[2][3]);
        #pragma unroll
        for (int off = 32; off >= 1; off >>= 1) {
            p0 += __shfl_xor(p0, off);
            p1 += __shfl_xor(p1, off);
            p2 += __shfl_xor(p2, off);
        }
        if (lane == 0) {
            const int row = wrow0 + i;
            d0[row] = p0; d1[row] = p1; d2[row] = p2;
        }
    }
}

// ---- k2: per batch: logits -> per-span (max, Z) -> per-row coefficient pack
// C[(b*512+m)*12 + s*4 + t] = (m+1-t in span s) ? exp(lg[m+1-t]-mx_s) : 0
__global__ __launch_bounds__(256)
void coef_kernel(const float* __restrict__ d0, const float* __restrict__ d1,
                 const float* __restrict__ d2, const int* __restrict__ offs,
                 float* __restrict__ C, float* __restrict__ Zv) {
    __shared__ float lg[L_];
    __shared__ float red[4];
    const int b = blockIdx.x, tid = threadIdx.x, lane = tid & 63, wv = tid >> 6;
    const size_t g = (size_t)b * L_;

    for (int l = tid; l < L_; l += 256) {
        float v = d1[g + l];
        if (l >= 1)      v += d0[g + l - 1];
        if (l <= L_ - 2) v += d2[g + l + 1];
        lg[l] = v;
    }
    __syncthreads();

    float mxr[3]; int str[3], enr[3];
    for (int s = 0; s < 3; ++s) {
        const int st = offs[b * 6 + s * 2], en = offs[b * 6 + s * 2 + 1]; // inclusive
        str[s] = st; enr[s] = en;
        float mx = -1e30f;
        for (int l = st + tid; l <= en; l += 256) mx = fmaxf(mx, lg[l]);
        #pragma unroll
        for (int off = 32; off >= 1; off >>= 1) mx = fmaxf(mx, __shfl_xor(mx, off));
        if (lane == 0) red[wv] = mx;
        __syncthreads();
        mx = fmaxf(fmaxf(red[0], red[1]), fmaxf(red[2], red[3]));
        __syncthreads();
        float sm = 0.f;
        for (int l = st + tid; l <= en; l += 256) sm += __expf(lg[l] - mx);
        #pragma unroll
        for (int off = 32; off >= 1; off >>= 1) sm += __shfl_xor(sm, off);
        if (lane == 0) red[wv] = sm;
        __syncthreads();
        const float dn = red[0] + red[1] + red[2] + red[3];
        if (tid == 0) Zv[b * 3 + s] = dn;
        __syncthreads();
        mxr[s] = mx;
    }

    for (int m = tid; m < L_; m += 256) {
        f32x4 c[3];
        #pragma unroll
        for (int s = 0; s < 3; ++s) {
            #pragma unroll
            for (int t = 0; t < 3; ++t) {
                const int l  = m + 1 - t;
                const int li = min(max(l, 0), L_ - 1);
                c[s][t] = (l >= str[s] && l <= enr[s]) ? __expf(lg[li] - mxr[s]) : 0.f;
            }
            c[s][3] = 0.f;
        }
        float* cp = C + ((size_t)(g + m)) * 12;
        *(f32x4*)(cp)     = c[0];
        *(f32x4*)(cp + 4) = c[1];
        *(f32x4*)(cp + 8) = c[2];
    }
}

// ---- k3: grid (b, sub8): each block scans its 64 X rows once, accumulating
// 9 weighted sums (3 spans x 3 taps). Rows with all-zero coeffs are skipped
// via a deterministic ballot-compacted list.
__global__ __launch_bounds__(256, 4)
void span_acc_kernel(const float* __restrict__ X, const float* __restrict__ C,
                     float* __restrict__ part) {
    __shared__ float cs[64][12];
    __shared__ unsigned char list[64];
    __shared__ int cnt;
    const int blk = blockIdx.x, b = blk >> 3, sub = blk & 7;
    const int tid = threadIdx.x;
    const int r0  = sub * 64;

    {   // stage the 64 C rows (3 KB, contiguous region)
        const int r = tid >> 2, q = tid & 3;
        if (q < 3)
            *(f32x4*)&cs[r][q * 4] =
                *(const f32x4*)(C + ((size_t)b * 512 + r0 + r) * 12 + q * 4);
    }
    __syncthreads();
    if (tid < 64) {
        bool flag = false;
        #pragma unroll
        for (int q = 0; q < 12; ++q) flag |= (cs[tid][q] != 0.f);
        unsigned long long mask = __ballot(flag);
        int pos = __popcll(mask & ((1ull << tid) - 1ull));
        if (flag) list[pos] = (unsigned char)tid;
        if (tid == 0) cnt = (int)__popcll(mask);
    }
    __syncthreads();
    const int n = cnt;

    f32x4 acc[9];
    #pragma unroll
    for (int i = 0; i < 9; ++i) acc[i] = (f32x4){0.f, 0.f, 0.f, 0.f};

    const float* Xb = X + ((size_t)b * 512 + r0) * 1024 + tid * 4;
    f32x4 xc = {}, xn = {};
    if (n > 0) xc = *(const f32x4*)(Xb + (size_t)list[0] * 1024);
    for (int j = 0; j < n; ++j) {
        if (j + 1 < n) xn = *(const f32x4*)(Xb + (size_t)list[j + 1] * 1024);
        const int r = list[j];
        #pragma unroll
        for (int s = 0; s < 3; ++s)
            #pragma unroll
            for (int t = 0; t < 3; ++t)
                acc[s * 3 + t] += cs[r][s * 4 + t] * xc;
        xc = xn;
    }

    float* pb = part + (size_t)(b * 8 + sub) * 9 * 1024 + tid * 4;
    #pragma unroll
    for (int i = 0; i < 9; ++i) *(f32x4*)(pb + i * 1024) = acc[i];
}

// ---- k4: per batch: reduce 8 partials -> ybar; emb via coalesced Wt2 dot;
// BN1 -> fc(192->512, coalesced fcT) -> ReLU -> BN2 -> concat -> last.
__global__ __launch_bounds__(256)
void head_kernel(const float* __restrict__ part, const float* __restrict__ Zv,
                 const float* __restrict__ Wt2, const float* __restrict__ cb,
                 const float* __restrict__ fcT,
                 const float* __restrict__ in_urls, const float* __restrict__ other,
                 const float* __restrict__ bn1_g, const float* __restrict__ bn1_b,
                 const float* __restrict__ bn1_m, const float* __restrict__ bn1_v,
                 const float* __restrict__ fc_b,
                 const float* __restrict__ bn2_g, const float* __restrict__ bn2_b,
                 const float* __restrict__ bn2_m, const float* __restrict__ bn2_v,
                 const float* __restrict__ last_w, const float* __restrict__ last_b,
                 float* __restrict__ out) {
    __shared__ float yb[9 * 1024];       // 36 KB
    __shared__ float emb[NSPANS * 64];
    __shared__ float hbuf[HIDDEN];

    const int b = blockIdx.x, tid = threadIdx.x, lane = tid & 63, wv = tid >> 6;

    #pragma unroll
    for (int i = 0; i < 9; ++i) {
        f32x4 v = (f32x4){0.f, 0.f, 0.f, 0.f};
        const float* p = part + (size_t)(b * 8) * 9 * 1024 + (size_t)i * 1024 + tid * 4;
        #pragma unroll
        for (int sub = 0; sub < 8; ++sub)
            v += *(const f32x4*)(p + (size_t)sub * 9 * 1024);
        *(f32x4*)&yb[i * 1024 + tid * 4] = v;
    }
    __syncthreads();

    if (tid < 192) {
        const int s = tid >> 6, o = tid & 63;
        float a0 = 0.f, a1 = 0.f, a2 = 0.f, a3 = 0.f;
        #pragma unroll
        for (int t = 0; t < 3; ++t) {
            const float* wp = Wt2 + (size_t)t * 65536 + o;    // [k][o], o coalesced
            const float* yp = &yb[(s * 3 + t) * 1024];
            for (int k = 0; k < 1024; k += 4) {
                a0 += wp[(size_t)(k + 0) * 64] * yp[k + 0];
                a1 += wp[(size_t)(k + 1) * 64] * yp[k + 1];
                a2 += wp[(size_t)(k + 2) * 64] * yp[k + 2];
                a3 += wp[(size_t)(k + 3) * 64] * yp[k + 3];
            }
        }
        const float ev = (a0 + a1 + a2 + a3) / Zv[b * 3 + s] + cb[o];
        emb[tid] = (ev - bn1_m[tid]) * rsqrtf(bn1_v[tid] + 1e-5f) * bn1_g[tid] + bn1_b[tid];
    }
    __syncthreads();

    #pragma unroll
    for (int q = 0; q < 2; ++q) {
        const int j = tid + q * 256;
        float s = fc_b[j];
        #pragma unroll 4
        for (int i = 0; i < NSPANS * 64; ++i)
            s += fcT[(size_t)i * 512 + j] * emb[i];           // j coalesced
        s = fmaxf(s, 0.f);
        hbuf[j] = (s - bn2_m[j]) * rsqrtf(bn2_v[j] + 1e-5f) * bn2_g[j] + bn2_b[j];
    }
    __syncthreads();

    if (wv < 3) {
        const float* lw = last_w + wv * (HIDDEN + 17);
        float s = 0.f;
        for (int i = lane; i < HIDDEN + 17; i += 64) {
            float f;
            if (i < HIDDEN)          f = hbuf[i];
            else if (i < HIDDEN + 3) f = in_urls[b * 3 + (i - HIDDEN)];
            else                     f = other[b * 14 + (i - HIDDEN - 3)];
            s += lw[i] * f;
        }
        #pragma unroll
        for (int off = 32; off >= 1; off >>= 1) s += __shfl_xor(s, off);
        if (lane == 0) out[b * 3 + wv] = s + last_b[wv];
    }
}

extern "C" void kernel_launch(void* const* d_in, const int* in_sizes, int n_in,
                              void* d_out, int out_size, void* d_ws, size_t ws_size,
                              hipStream_t stream) {
    const float* bert    = (const float*)d_in[0];
    const int*   offs    = (const int*)d_in[1];
    const float* in_urls = (const float*)d_in[2];
    const float* other   = (const float*)d_in[3];
    const float* conv_w  = (const float*)d_in[4];
    const float* conv_b  = (const float*)d_in[5];
    const float* att_w   = (const float*)d_in[6];
    // att_b cancels in the softmax shift — unused.
    const float* bn1_g   = (const float*)d_in[8];
    const float* bn1_b   = (const float*)d_in[9];
    const float* bn1_m   = (const float*)d_in[10];
    const float* bn1_v   = (const float*)d_in[11];
    const float* fc_w    = (const float*)d_in[12];
    const float* fc_b    = (const float*)d_in[13];
    const float* bn2_g   = (const float*)d_in[14];
    const float* bn2_b   = (const float*)d_in[15];
    const float* bn2_m   = (const float*)d_in[16];
    const float* bn2_v   = (const float*)d_in[17];
    const float* last_w  = (const float*)d_in[18];
    const float* last_b  = (const float*)d_in[19];

    // ws layout (bytes):
    //   u    @ 0          (12,288)
    //   Wt2  @ 12,288     (786,432)
    //   fcT  @ 798,720    (393,216)
    //   d0   @ 1,191,936  (262,144)
    //   d1   @ 1,454,080  (262,144)
    //   d2   @ 1,716,224  (262,144)
    //   Zv   @ 1,978,368  (1,536)
    //   C    @ 1,979,904  (3,145,728)
    //   part @ 5,125,632  (37,748,736)     total ~42.9 MB
    float* u    = (float*)d_ws;
    float* Wt2  = (float*)((char*)d_ws + 12288);
    float* fcT  = (float*)((char*)d_ws + 798720);
    float* d0   = (float*)((char*)d_ws + 1191936);
    float* d1   = (float*)((char*)d_ws + 1454080);
    float* d2   = (float*)((char*)d_ws + 1716224);
    float* Zv   = (float*)((char*)d_ws + 1978368);
    float* C    = (float*)((char*)d_ws + 1979904);
    float* part = (float*)((char*)d_ws + 5125632);

    hipLaunchKernelGGL(prep_kernel, dim3(96), dim3(256), 0, stream,
                       conv_w, att_w, fc_w, u, Wt2, fcT);
    hipLaunchKernelGGL(dots_kernel, dim3((B_ * L_) / 32), dim3(256), 0, stream,
                       bert, u, d0, d1, d2);
    hipLaunchKernelGGL(coef_kernel, dim3(B_), dim3(256), 0, stream,
                       d0, d1, d2, offs, C, Zv);
    hipLaunchKernelGGL(span_acc_kernel, dim3(B_ * 8), dim3(256), 0, stream,
                       bert, C, part);
    hipLaunchKernelGGL(head_kernel, dim3(B_), dim3(256), 0, stream,
                       part, Zv, Wt2, conv_b, fcT, in_urls, other,
                       bn1_g, bn1_b, bn1_m, bn1_v, fc_b,
                       bn2_g, bn2_b, bn2_m, bn2_v, last_w, last_b,
                       (float*)d_out);
}

// Round 8
// 219.781 us; speedup vs baseline: 1.1343x; 1.1343x over previous
//
#include <hip/hip_runtime.h>

// ---------------------------------------------------------------------------
// Head_87033217286245 — Round 8. Algebra identical to R6/R7 (absmax 0):
//   d_t = X·u_t ; logits from d ; softmax coeffs C ; ybar = C-weighted row sums;
//   emb = Wt2·ybar/Z + cb ; BN/fc/BN/last.
// R8 fixes the load-level-parallelism hole in both X-streaming kernels:
//   dots: 2-row software pipeline (8 coalesced loads in flight per wave).
//   span_acc: wave = 64 rows x 1KB quad-segment, 4-row chunks (4 loads in
//   flight), LDS-staged coeffs, uniform skip, deterministic 4-wave reduce.
// ---------------------------------------------------------------------------

typedef float f32x4 __attribute__((ext_vector_type(4)));

#define B_      128
#define L_      512
#define NSPANS  3
#define HIDDEN  512

__device__ __forceinline__ float dp4(f32x4 a, f32x4 b) {
    return a.x*b.x + a.y*b.y + a.z*b.z + a.w*b.w;
}

// ---- k0: u_t[k] = Sum_o W[o,k,t]*aw[o];  Wt2[t][k][o];  fcT[i][j]
__global__ __launch_bounds__(256)
void prep_kernel(const float* __restrict__ cw, const float* __restrict__ aw,
                 const float* __restrict__ fcw,
                 float* __restrict__ u, float* __restrict__ Wt2,
                 float* __restrict__ fcT) {
    const int idx = blockIdx.x * 256 + threadIdx.x;      // 96*256 = 24576
    if (idx < 3072) {
        const int t = idx >> 10, k = idx & 1023;
        float s = 0.f;
        #pragma unroll 8
        for (int o = 0; o < 64; ++o)
            s += cw[(size_t)(o * 1024 + k) * 3 + t] * aw[o];
        u[idx] = s;
    }
    for (int i = idx; i < 196608; i += 24576) {          // Wt2[(t*1024+k)*64+o]
        const int o = i & 63, k = (i >> 6) & 1023, t = i >> 16;
        Wt2[i] = cw[(size_t)(o * 1024 + k) * 3 + t];
    }
    for (int i = idx; i < 98304; i += 24576) {           // fcT[r*512+j] = fcw[j*192+r]
        const int j = i & 511, r = i >> 9;
        fcT[i] = fcw[(size_t)j * 192 + r];
    }
}

// ---- k1: d_t[m] = X[m,:]·u_t. 1024 blocks x 4 waves; wave = 16 rows.
// Named-buffer 2-row pipeline: 8 independent 1KB-coalesced loads in flight.
__global__ __launch_bounds__(256, 4)
void dots_kernel(const float* __restrict__ X, const float* __restrict__ u,
                 float* __restrict__ d0, float* __restrict__ d1,
                 float* __restrict__ d2) {
    const int tid = threadIdx.x, lane = tid & 63, wv = tid >> 6;
    f32x4 uu[3][4];
    #pragma unroll
    for (int t = 0; t < 3; ++t)
        #pragma unroll
        for (int q = 0; q < 4; ++q)
            uu[t][q] = *(const f32x4*)(u + t * 1024 + q * 256 + lane * 4);

    const int wrow0 = (blockIdx.x * 4 + wv) * 16;
    const float* xp = X + (size_t)wrow0 * 1024 + lane * 4;

    f32x4 xA0, xA1, xA2, xA3, xB0, xB1, xB2, xB3;
    #define LOADA(off) { const float* rp = xp + (size_t)(off) * 1024; \
        xA0 = *(const f32x4*)(rp);       xA1 = *(const f32x4*)(rp + 256); \
        xA2 = *(const f32x4*)(rp + 512); xA3 = *(const f32x4*)(rp + 768); }
    #define LOADB(off) { const float* rp = xp + (size_t)(off) * 1024; \
        xB0 = *(const f32x4*)(rp);       xB1 = *(const f32x4*)(rp + 256); \
        xB2 = *(const f32x4*)(rp + 512); xB3 = *(const f32x4*)(rp + 768); }
    #define REDSTORE(q0,q1,q2,q3,row) { \
        float p0 = dp4(q0,uu[0][0])+dp4(q1,uu[0][1])+dp4(q2,uu[0][2])+dp4(q3,uu[0][3]); \
        float p1 = dp4(q0,uu[1][0])+dp4(q1,uu[1][1])+dp4(q2,uu[1][2])+dp4(q3,uu[1][3]); \
        float p2 = dp4(q0,uu[2][0])+dp4(q1,uu[2][1])+dp4(q2,uu[2][2])+dp4(q3,uu[2][3]); \
        _Pragma("unroll") \
        for (int off = 32; off >= 1; off >>= 1) { \
            p0 += __shfl_xor(p0, off); p1 += __shfl_xor(p1, off); p2 += __shfl_xor(p2, off); } \
        if (lane == 0) { d0[wrow0+(row)] = p0; d1[wrow0+(row)] = p1; d2[wrow0+(row)] = p2; } }

    LOADA(0)
    #pragma unroll
    for (int i = 0; i < 16; i += 2) {
        if (i + 1 < 16) LOADB(i + 1)
        REDSTORE(xA0, xA1, xA2, xA3, i)
        if (i + 2 < 16) LOADA(i + 2)
        REDSTORE(xB0, xB1, xB2, xB3, i + 1)
    }
    #undef LOADA
    #undef LOADB
    #undef REDSTORE
}

// ---- k2: per batch: logits -> per-span (max, Z) -> per-row coeff pack
// C[(b*512+m)*12 + s*4 + t] = (m+1-t in span s) ? exp(lg[m+1-t]-mx_s) : 0
__global__ __launch_bounds__(256)
void coef_kernel(const float* __restrict__ d0, const float* __restrict__ d1,
                 const float* __restrict__ d2, const int* __restrict__ offs,
                 float* __restrict__ C, float* __restrict__ Zv) {
    __shared__ float lg[L_];
    __shared__ float red[4];
    const int b = blockIdx.x, tid = threadIdx.x, lane = tid & 63, wv = tid >> 6;
    const size_t g = (size_t)b * L_;

    for (int l = tid; l < L_; l += 256) {
        float v = d1[g + l];
        if (l >= 1)      v += d0[g + l - 1];
        if (l <= L_ - 2) v += d2[g + l + 1];
        lg[l] = v;
    }
    __syncthreads();

    float mxr[3]; int str[3], enr[3];
    for (int s = 0; s < 3; ++s) {
        const int st = offs[b * 6 + s * 2], en = offs[b * 6 + s * 2 + 1]; // inclusive
        str[s] = st; enr[s] = en;
        float mx = -1e30f;
        for (int l = st + tid; l <= en; l += 256) mx = fmaxf(mx, lg[l]);
        #pragma unroll
        for (int off = 32; off >= 1; off >>= 1) mx = fmaxf(mx, __shfl_xor(mx, off));
        if (lane == 0) red[wv] = mx;
        __syncthreads();
        mx = fmaxf(fmaxf(red[0], red[1]), fmaxf(red[2], red[3]));
        __syncthreads();
        float sm = 0.f;
        for (int l = st + tid; l <= en; l += 256) sm += __expf(lg[l] - mx);
        #pragma unroll
        for (int off = 32; off >= 1; off >>= 1) sm += __shfl_xor(sm, off);
        if (lane == 0) red[wv] = sm;
        __syncthreads();
        if (tid == 0) Zv[b * 3 + s] = red[0] + red[1] + red[2] + red[3];
        __syncthreads();
        mxr[s] = mx;
    }

    for (int m = tid; m < L_; m += 256) {
        f32x4 c[3];
        #pragma unroll
        for (int s = 0; s < 3; ++s) {
            #pragma unroll
            for (int t = 0; t < 3; ++t) {
                const int l  = m + 1 - t;
                const int li = min(max(l, 0), L_ - 1);
                c[s][t] = (l >= str[s] && l <= enr[s]) ? __expf(lg[li] - mxr[s]) : 0.f;
            }
            c[s][3] = 0.f;
        }
        float* cp = C + ((size_t)(g + m)) * 12;
        *(f32x4*)(cp)     = c[0];
        *(f32x4*)(cp + 4) = c[1];
        *(f32x4*)(cp + 8) = c[2];
    }
}

// ---- k3: block (b, q, h): wave v owns rows [h*256+v*64, +64) x k-quad q.
// 4-row chunks -> 4 independent coalesced 1KB loads in flight; uniform skip.
__global__ __launch_bounds__(256, 4)
void span_acc_kernel(const float* __restrict__ X, const float* __restrict__ C,
                     float* __restrict__ part) {
    __shared__ float cs[256 * 12];           // 12 KB, rows h*256..+256
    __shared__ unsigned char flg[256];
    __shared__ float rbuf[256 * 4];          // 4 KB reduce buffer

    const int blk = blockIdx.x;              // 1024
    const int b = blk >> 3, p = blk & 7;
    const int q = p >> 1, h = p & 1;
    const int tid = threadIdx.x, lane = tid & 63, wv = tid >> 6;

    {   // stage 256 C rows (contiguous 12 KB)
        const float* cp = C + ((size_t)b * 512 + h * 256) * 12;
        #pragma unroll
        for (int w = 0; w < 3; ++w)
            *(f32x4*)&cs[(tid + w * 256) * 4] = *(const f32x4*)(cp + (tid + w * 256) * 4);
    }
    __syncthreads();
    {   // per-row any-nonzero flag
        const float* cr = &cs[tid * 12];
        float s = 0.f;
        #pragma unroll
        for (int j = 0; j < 12; ++j) s += fabsf(cr[j]);
        flg[tid] = (s != 0.f) ? 1 : 0;
    }
    __syncthreads();

    f32x4 acc[9];
    #pragma unroll
    for (int a = 0; a < 9; ++a) acc[a] = (f32x4){0.f, 0.f, 0.f, 0.f};

    const float* Xw = X + ((size_t)b * 512 + h * 256 + wv * 64) * 1024 + q * 256 + lane * 4;
    const int rbase = wv * 64;

    for (int c = 0; c < 16; ++c) {
        const int r0 = rbase + c * 4;
        if ((flg[r0] | flg[r0 + 1] | flg[r0 + 2] | flg[r0 + 3]) == 0) continue;
        f32x4 x0 = *(const f32x4*)(Xw + (size_t)(c * 4 + 0) * 1024);
        f32x4 x1 = *(const f32x4*)(Xw + (size_t)(c * 4 + 1) * 1024);
        f32x4 x2 = *(const f32x4*)(Xw + (size_t)(c * 4 + 2) * 1024);
        f32x4 x3 = *(const f32x4*)(Xw + (size_t)(c * 4 + 3) * 1024);
        #define ROWFMA(xr, rr) { \
            f32x4 c0 = *(const f32x4*)&cs[(rr) * 12]; \
            f32x4 c1 = *(const f32x4*)&cs[(rr) * 12 + 4]; \
            f32x4 c2 = *(const f32x4*)&cs[(rr) * 12 + 8]; \
            acc[0] += c0.x * xr; acc[1] += c0.y * xr; acc[2] += c0.z * xr; \
            acc[3] += c1.x * xr; acc[4] += c1.y * xr; acc[5] += c1.z * xr; \
            acc[6] += c2.x * xr; acc[7] += c2.y * xr; acc[8] += c2.z * xr; }
        ROWFMA(x0, r0)
        ROWFMA(x1, r0 + 1)
        ROWFMA(x2, r0 + 2)
        ROWFMA(x3, r0 + 3)
        #undef ROWFMA
    }

    // deterministic 4-wave reduce, one acc at a time
    float* pb = part + (size_t)blk * 2304;   // 9*256
    #pragma unroll
    for (int a = 0; a < 9; ++a) {
        __syncthreads();
        *(f32x4*)&rbuf[tid * 4] = acc[a];
        __syncthreads();
        if (tid < 64) {
            f32x4 s = *(const f32x4*)&rbuf[tid * 4];
            s += *(const f32x4*)&rbuf[(64 + tid) * 4];
            s += *(const f32x4*)&rbuf[(128 + tid) * 4];
            s += *(const f32x4*)&rbuf[(192 + tid) * 4];
            *(f32x4*)(pb + a * 256 + tid * 4) = s;
        }
    }
}

// ---- k4: per batch: reduce 2 partials -> ybar; emb via coalesced Wt2 dot;
// BN1 -> fc(coalesced fcT) -> ReLU -> BN2 -> concat -> last.
__global__ __launch_bounds__(256)
void head_kernel(const float* __restrict__ part, const float* __restrict__ Zv,
                 const float* __restrict__ Wt2, const float* __restrict__ cb,
                 const float* __restrict__ fcT,
                 const float* __restrict__ in_urls, const float* __restrict__ other,
                 const float* __restrict__ bn1_g, const float* __restrict__ bn1_b,
                 const float* __restrict__ bn1_m, const float* __restrict__ bn1_v,
                 const float* __restrict__ fc_b,
                 const float* __restrict__ bn2_g, const float* __restrict__ bn2_b,
                 const float* __restrict__ bn2_m, const float* __restrict__ bn2_v,
                 const float* __restrict__ last_w, const float* __restrict__ last_b,
                 float* __restrict__ out) {
    __shared__ float yb[9 * 1024];       // 36 KB
    __shared__ float emb[NSPANS * 64];
    __shared__ float hbuf[HIDDEN];

    const int b = blockIdx.x, tid = threadIdx.x, lane = tid & 63, wv = tid >> 6;

    {   // yb[i][k] = sum_h part[(b*8 + (k>>8)*2 + h)][i*256 + (k&255)]
        const int q = tid >> 6, pos = (tid & 63) * 4;
        const float* p0 = part + (size_t)(b * 8 + q * 2 + 0) * 2304 + pos;
        const float* p1 = part + (size_t)(b * 8 + q * 2 + 1) * 2304 + pos;
        #pragma unroll
        for (int i = 0; i < 9; ++i) {
            f32x4 v = *(const f32x4*)(p0 + i * 256) + *(const f32x4*)(p1 + i * 256);
            *(f32x4*)&yb[i * 1024 + q * 256 + pos] = v;
        }
    }
    __syncthreads();

    if (tid < 192) {
        const int s = tid >> 6, o = tid & 63;
        float a0 = 0.f, a1 = 0.f, a2 = 0.f, a3 = 0.f;
        #pragma unroll
        for (int t = 0; t < 3; ++t) {
            const float* wp = Wt2 + (size_t)t * 65536 + o;    // [k][o], o coalesced
            const float* yp = &yb[(s * 3 + t) * 1024];
            for (int k = 0; k < 1024; k += 4) {
                a0 += wp[(size_t)(k + 0) * 64] * yp[k + 0];
                a1 += wp[(size_t)(k + 1) * 64] * yp[k + 1];
                a2 += wp[(size_t)(k + 2) * 64] * yp[k + 2];
                a3 += wp[(size_t)(k + 3) * 64] * yp[k + 3];
            }
        }
        const float ev = (a0 + a1 + a2 + a3) / Zv[b * 3 + s] + cb[o];
        emb[tid] = (ev - bn1_m[tid]) * rsqrtf(bn1_v[tid] + 1e-5f) * bn1_g[tid] + bn1_b[tid];
    }
    __syncthreads();

    #pragma unroll
    for (int qq = 0; qq < 2; ++qq) {
        const int j = tid + qq * 256;
        float s = fc_b[j];
        #pragma unroll 4
        for (int i = 0; i < NSPANS * 64; ++i)
            s += fcT[(size_t)i * 512 + j] * emb[i];           // j coalesced
        s = fmaxf(s, 0.f);
        hbuf[j] = (s - bn2_m[j]) * rsqrtf(bn2_v[j] + 1e-5f) * bn2_g[j] + bn2_b[j];
    }
    __syncthreads();

    if (wv < 3) {
        const float* lw = last_w + wv * (HIDDEN + 17);
        float s = 0.f;
        for (int i = lane; i < HIDDEN + 17; i += 64) {
            float f;
            if (i < HIDDEN)          f = hbuf[i];
            else if (i < HIDDEN + 3) f = in_urls[b * 3 + (i - HIDDEN)];
            else                     f = other[b * 14 + (i - HIDDEN - 3)];
            s += lw[i] * f;
        }
        #pragma unroll
        for (int off = 32; off >= 1; off >>= 1) s += __shfl_xor(s, off);
        if (lane == 0) out[b * 3 + wv] = s + last_b[wv];
    }
}

extern "C" void kernel_launch(void* const* d_in, const int* in_sizes, int n_in,
                              void* d_out, int out_size, void* d_ws, size_t ws_size,
                              hipStream_t stream) {
    const float* bert    = (const float*)d_in[0];
    const int*   offs    = (const int*)d_in[1];
    const float* in_urls = (const float*)d_in[2];
    const float* other   = (const float*)d_in[3];
    const float* conv_w  = (const float*)d_in[4];
    const float* conv_b  = (const float*)d_in[5];
    const float* att_w   = (const float*)d_in[6];
    // att_b cancels in the softmax shift — unused.
    const float* bn1_g   = (const float*)d_in[8];
    const float* bn1_b   = (const float*)d_in[9];
    const float* bn1_m   = (const float*)d_in[10];
    const float* bn1_v   = (const float*)d_in[11];
    const float* fc_w    = (const float*)d_in[12];
    const float* fc_b    = (const float*)d_in[13];
    const float* bn2_g   = (const float*)d_in[14];
    const float* bn2_b   = (const float*)d_in[15];
    const float* bn2_m   = (const float*)d_in[16];
    const float* bn2_v   = (const float*)d_in[17];
    const float* last_w  = (const float*)d_in[18];
    const float* last_b  = (const float*)d_in[19];

    // ws layout (bytes):
    //   u    @ 0          (12,288)
    //   Wt2  @ 12,288     (786,432)
    //   fcT  @ 798,720    (393,216)
    //   d0   @ 1,191,936  (262,144)
    //   d1   @ 1,454,080  (262,144)
    //   d2   @ 1,716,224  (262,144)
    //   Zv   @ 1,978,368  (1,536)
    //   C    @ 1,979,904  (3,145,728)
    //   part @ 5,125,632  (9,437,184)      total ~14.6 MB
    float* u    = (float*)d_ws;
    float* Wt2  = (float*)((char*)d_ws + 12288);
    float* fcT  = (float*)((char*)d_ws + 798720);
    float* d0   = (float*)((char*)d_ws + 1191936);
    float* d1   = (float*)((char*)d_ws + 1454080);
    float* d2   = (float*)((char*)d_ws + 1716224);
    float* Zv   = (float*)((char*)d_ws + 1978368);
    float* C    = (float*)((char*)d_ws + 1979904);
    float* part = (float*)((char*)d_ws + 5125632);

    hipLaunchKernelGGL(prep_kernel, dim3(96), dim3(256), 0, stream,
                       conv_w, att_w, fc_w, u, Wt2, fcT);
    hipLaunchKernelGGL(dots_kernel, dim3((B_ * L_) / 64), dim3(256), 0, stream,
                       bert, u, d0, d1, d2);
    hipLaunchKernelGGL(coef_kernel, dim3(B_), dim3(256), 0, stream,
                       d0, d1, d2, offs, C, Zv);
    hipLaunchKernelGGL(span_acc_kernel, dim3(B_ * 8), dim3(256), 0, stream,
                       bert, C, part);
    hipLaunchKernelGGL(head_kernel, dim3(B_), dim3(256), 0, stream,
                       part, Zv, Wt2, conv_b, fcT, in_urls, other,
                       bn1_g, bn1_b, bn1_m, bn1_v, fc_b,
                       bn2_g, bn2_b, bn2_m, bn2_v, last_w, last_b,
                       (float*)d_out);
}

// Round 9
// 216.635 us; speedup vs baseline: 1.1508x; 1.0145x over previous
//
#include <hip/hip_runtime.h>

// ---------------------------------------------------------------------------
// Head_87033217286245 — Round 9. Algebra identical to R6-R8 (absmax 0).
// dots rebuilt as a DENSE-SWEEP grid-stride reader (m13-copy shape): block-
// per-row, consecutive blocks on consecutive rows at the same instant, 2-row
// register pipeline. R1-R8's readers all gave each wave a private serial
// segment (scattered instantaneous footprint) and none exceeded ~2 TB/s.
// ---------------------------------------------------------------------------

typedef float f32x4 __attribute__((ext_vector_type(4)));

#define B_      128
#define L_      512
#define NSPANS  3
#define HIDDEN  512
#define DG      4096          // dots grid; 65536 rows / 4096 = 16 rows/block

__device__ __forceinline__ float dp4(f32x4 a, f32x4 b) {
    return a.x*b.x + a.y*b.y + a.z*b.z + a.w*b.w;
}

// ---- k0: u_t[k] = Sum_o W[o,k,t]*aw[o];  Wt2[t][k][o];  fcT[i][j]
__global__ __launch_bounds__(256)
void prep_kernel(const float* __restrict__ cw, const float* __restrict__ aw,
                 const float* __restrict__ fcw,
                 float* __restrict__ u, float* __restrict__ Wt2,
                 float* __restrict__ fcT) {
    const int idx = blockIdx.x * 256 + threadIdx.x;      // 96*256 = 24576
    if (idx < 3072) {
        const int t = idx >> 10, k = idx & 1023;
        float s = 0.f;
        #pragma unroll 8
        for (int o = 0; o < 64; ++o)
            s += cw[(size_t)(o * 1024 + k) * 3 + t] * aw[o];
        u[idx] = s;
    }
    for (int i = idx; i < 196608; i += 24576) {          // Wt2[(t*1024+k)*64+o]
        const int o = i & 63, k = (i >> 6) & 1023, t = i >> 16;
        Wt2[i] = cw[(size_t)(o * 1024 + k) * 3 + t];
    }
    for (int i = idx; i < 98304; i += 24576) {           // fcT[r*512+j] = fcw[j*192+r]
        const int j = i & 511, r = i >> 9;
        fcT[i] = fcw[(size_t)j * 192 + r];
    }
}

// ---- k1: d_t[m] = X[m,:]·u_t. DENSE SWEEP: block-per-row grid-stride.
// Block b step i handles row b + i*DG; 256 threads x float4 = the whole row.
__global__ __launch_bounds__(256, 4)
void dots_kernel(const float* __restrict__ X, const float* __restrict__ u,
                 float* __restrict__ d0, float* __restrict__ d1,
                 float* __restrict__ d2) {
    __shared__ float red[12];
    const int tid = threadIdx.x, lane = tid & 63, wv = tid >> 6;

    const f32x4 u0 = *(const f32x4*)(u + tid * 4);
    const f32x4 u1 = *(const f32x4*)(u + 1024 + tid * 4);
    const f32x4 u2 = *(const f32x4*)(u + 2048 + tid * 4);

    int row = blockIdx.x;
    f32x4 xA = *(const f32x4*)(X + (size_t)row * 1024 + tid * 4);
    f32x4 xB;

    #pragma unroll 4
    for (int i = 0; i < 16; ++i) {
        const int nrow = row + DG;
        if (i + 1 < 16)
            xB = *(const f32x4*)(X + (size_t)nrow * 1024 + tid * 4);

        float p0 = dp4(xA, u0), p1 = dp4(xA, u1), p2 = dp4(xA, u2);
        #pragma unroll
        for (int off = 32; off >= 1; off >>= 1) {
            p0 += __shfl_xor(p0, off);
            p1 += __shfl_xor(p1, off);
            p2 += __shfl_xor(p2, off);
        }
        if (lane == 0) {
            red[wv * 3 + 0] = p0; red[wv * 3 + 1] = p1; red[wv * 3 + 2] = p2;
        }
        __syncthreads();
        if (tid < 3) {
            const float s = red[tid] + red[3 + tid] + red[6 + tid] + red[9 + tid];
            float* dst = (tid == 0) ? d0 : (tid == 1) ? d1 : d2;
            dst[row] = s;
        }
        __syncthreads();
        xA = xB;
        row = nrow;
    }
}

// ---- k2: per batch: logits -> per-span (max, Z) -> per-row coeff pack
// C[(b*512+m)*12 + s*4 + t] = (m+1-t in span s) ? exp(lg[m+1-t]-mx_s) : 0
__global__ __launch_bounds__(256)
void coef_kernel(const float* __restrict__ d0, const float* __restrict__ d1,
                 const float* __restrict__ d2, const int* __restrict__ offs,
                 float* __restrict__ C, float* __restrict__ Zv) {
    __shared__ float lg[L_];
    __shared__ float red[4];
    const int b = blockIdx.x, tid = threadIdx.x, lane = tid & 63, wv = tid >> 6;
    const size_t g = (size_t)b * L_;

    for (int l = tid; l < L_; l += 256) {
        float v = d1[g + l];
        if (l >= 1)      v += d0[g + l - 1];
        if (l <= L_ - 2) v += d2[g + l + 1];
        lg[l] = v;
    }
    __syncthreads();

    float mxr[3]; int str[3], enr[3];
    for (int s = 0; s < 3; ++s) {
        const int st = offs[b * 6 + s * 2], en = offs[b * 6 + s * 2 + 1]; // inclusive
        str[s] = st; enr[s] = en;
        float mx = -1e30f;
        for (int l = st + tid; l <= en; l += 256) mx = fmaxf(mx, lg[l]);
        #pragma unroll
        for (int off = 32; off >= 1; off >>= 1) mx = fmaxf(mx, __shfl_xor(mx, off));
        if (lane == 0) red[wv] = mx;
        __syncthreads();
        mx = fmaxf(fmaxf(red[0], red[1]), fmaxf(red[2], red[3]));
        __syncthreads();
        float sm = 0.f;
        for (int l = st + tid; l <= en; l += 256) sm += __expf(lg[l] - mx);
        #pragma unroll
        for (int off = 32; off >= 1; off >>= 1) sm += __shfl_xor(sm, off);
        if (lane == 0) red[wv] = sm;
        __syncthreads();
        if (tid == 0) Zv[b * 3 + s] = red[0] + red[1] + red[2] + red[3];
        __syncthreads();
        mxr[s] = mx;
    }

    for (int m = tid; m < L_; m += 256) {
        f32x4 c[3];
        #pragma unroll
        for (int s = 0; s < 3; ++s) {
            #pragma unroll
            for (int t = 0; t < 3; ++t) {
                const int l  = m + 1 - t;
                const int li = min(max(l, 0), L_ - 1);
                c[s][t] = (l >= str[s] && l <= enr[s]) ? __expf(lg[li] - mxr[s]) : 0.f;
            }
            c[s][3] = 0.f;
        }
        float* cp = C + ((size_t)(g + m)) * 12;
        *(f32x4*)(cp)     = c[0];
        *(f32x4*)(cp + 4) = c[1];
        *(f32x4*)(cp + 8) = c[2];
    }
}

// ---- k3: block (b, q, h): wave v owns rows [h*256+v*64, +64) x k-quad q.
// 4-row chunks -> 4 coalesced loads in flight; whole-block zero skip.
__global__ __launch_bounds__(256, 4)
void span_acc_kernel(const float* __restrict__ X, const float* __restrict__ C,
                     float* __restrict__ part) {
    __shared__ float cs[256 * 12];           // 12 KB
    __shared__ unsigned char flg[256];
    __shared__ int wany[4];
    __shared__ float rbuf[256 * 4];          // 4 KB reduce buffer

    const int blk = blockIdx.x;              // 1024
    const int b = blk >> 3, p = blk & 7;
    const int q = p >> 1, h = p & 1;
    const int tid = threadIdx.x, lane = tid & 63, wv = tid >> 6;
    float* pb = part + (size_t)blk * 2304;   // 9*256

    {   // stage 256 C rows (contiguous 12 KB)
        const float* cp = C + ((size_t)b * 512 + h * 256) * 12;
        #pragma unroll
        for (int w = 0; w < 3; ++w)
            *(f32x4*)&cs[(tid + w * 256) * 4] = *(const f32x4*)(cp + (tid + w * 256) * 4);
    }
    __syncthreads();
    {   // per-row any-nonzero flag + whole-block flag
        const float* cr = &cs[tid * 12];
        float s = 0.f;
        #pragma unroll
        for (int j = 0; j < 12; ++j) s += fabsf(cr[j]);
        const bool f = (s != 0.f);
        flg[tid] = f ? 1 : 0;
        const unsigned long long m = __ballot(f);
        if (lane == 0) wany[wv] = (m != 0ull) ? 1 : 0;
    }
    __syncthreads();
    if ((wany[0] | wany[1] | wany[2] | wany[3]) == 0) {
        for (int i = tid; i < 2304; i += 256) pb[i] = 0.f;
        return;
    }

    f32x4 acc[9];
    #pragma unroll
    for (int a = 0; a < 9; ++a) acc[a] = (f32x4){0.f, 0.f, 0.f, 0.f};

    const float* Xw = X + ((size_t)b * 512 + h * 256 + wv * 64) * 1024 + q * 256 + lane * 4;
    const int rbase = wv * 64;

    for (int c = 0; c < 16; ++c) {
        const int r0 = rbase + c * 4;
        if ((flg[r0] | flg[r0 + 1] | flg[r0 + 2] | flg[r0 + 3]) == 0) continue;
        f32x4 x0 = *(const f32x4*)(Xw + (size_t)(c * 4 + 0) * 1024);
        f32x4 x1 = *(const f32x4*)(Xw + (size_t)(c * 4 + 1) * 1024);
        f32x4 x2 = *(const f32x4*)(Xw + (size_t)(c * 4 + 2) * 1024);
        f32x4 x3 = *(const f32x4*)(Xw + (size_t)(c * 4 + 3) * 1024);
        #define ROWFMA(xr, rr) { \
            f32x4 c0 = *(const f32x4*)&cs[(rr) * 12]; \
            f32x4 c1 = *(const f32x4*)&cs[(rr) * 12 + 4]; \
            f32x4 c2 = *(const f32x4*)&cs[(rr) * 12 + 8]; \
            acc[0] += c0.x * xr; acc[1] += c0.y * xr; acc[2] += c0.z * xr; \
            acc[3] += c1.x * xr; acc[4] += c1.y * xr; acc[5] += c1.z * xr; \
            acc[6] += c2.x * xr; acc[7] += c2.y * xr; acc[8] += c2.z * xr; }
        ROWFMA(x0, r0)
        ROWFMA(x1, r0 + 1)
        ROWFMA(x2, r0 + 2)
        ROWFMA(x3, r0 + 3)
        #undef ROWFMA
    }

    // deterministic 4-wave reduce, one acc at a time
    #pragma unroll
    for (int a = 0; a < 9; ++a) {
        __syncthreads();
        *(f32x4*)&rbuf[tid * 4] = acc[a];
        __syncthreads();
        if (tid < 64) {
            f32x4 s = *(const f32x4*)&rbuf[tid * 4];
            s += *(const f32x4*)&rbuf[(64 + tid) * 4];
            s += *(const f32x4*)&rbuf[(128 + tid) * 4];
            s += *(const f32x4*)&rbuf[(192 + tid) * 4];
            *(f32x4*)(pb + a * 256 + tid * 4) = s;
        }
    }
}

// ---- k4: per batch: reduce 2 partials -> ybar; emb via coalesced Wt2 dot;
// BN1 -> fc(coalesced fcT) -> ReLU -> BN2 -> concat -> last.
__global__ __launch_bounds__(256)
void head_kernel(const float* __restrict__ part, const float* __restrict__ Zv,
                 const float* __restrict__ Wt2, const float* __restrict__ cb,
                 const float* __restrict__ fcT,
                 const float* __restrict__ in_urls, const float* __restrict__ other,
                 const float* __restrict__ bn1_g, const float* __restrict__ bn1_b,
                 const float* __restrict__ bn1_m, const float* __restrict__ bn1_v,
                 const float* __restrict__ fc_b,
                 const float* __restrict__ bn2_g, const float* __restrict__ bn2_b,
                 const float* __restrict__ bn2_m, const float* __restrict__ bn2_v,
                 const float* __restrict__ last_w, const float* __restrict__ last_b,
                 float* __restrict__ out) {
    __shared__ float yb[9 * 1024];       // 36 KB
    __shared__ float emb[NSPANS * 64];
    __shared__ float hbuf[HIDDEN];

    const int b = blockIdx.x, tid = threadIdx.x, lane = tid & 63, wv = tid >> 6;

    {   // yb[i][k] = sum_h part[(b*8 + (k>>8)*2 + h)][i*256 + (k&255)]
        const int q = tid >> 6, pos = (tid & 63) * 4;
        const float* p0 = part + (size_t)(b * 8 + q * 2 + 0) * 2304 + pos;
        const float* p1 = part + (size_t)(b * 8 + q * 2 + 1) * 2304 + pos;
        #pragma unroll
        for (int i = 0; i < 9; ++i) {
            f32x4 v = *(const f32x4*)(p0 + i * 256) + *(const f32x4*)(p1 + i * 256);
            *(f32x4*)&yb[i * 1024 + q * 256 + pos] = v;
        }
    }
    __syncthreads();

    if (tid < 192) {
        const int s = tid >> 6, o = tid & 63;
        float a0 = 0.f, a1 = 0.f, a2 = 0.f, a3 = 0.f;
        #pragma unroll
        for (int t = 0; t < 3; ++t) {
            const float* wp = Wt2 + (size_t)t * 65536 + o;    // [k][o], o coalesced
            const float* yp = &yb[(s * 3 + t) * 1024];
            for (int k = 0; k < 1024; k += 4) {
                a0 += wp[(size_t)(k + 0) * 64] * yp[k + 0];
                a1 += wp[(size_t)(k + 1) * 64] * yp[k + 1];
                a2 += wp[(size_t)(k + 2) * 64] * yp[k + 2];
                a3 += wp[(size_t)(k + 3) * 64] * yp[k + 3];
            }
        }
        const float ev = (a0 + a1 + a2 + a3) / Zv[b * 3 + s] + cb[o];
        emb[tid] = (ev - bn1_m[tid]) * rsqrtf(bn1_v[tid] + 1e-5f) * bn1_g[tid] + bn1_b[tid];
    }
    __syncthreads();

    #pragma unroll
    for (int qq = 0; qq < 2; ++qq) {
        const int j = tid + qq * 256;
        float s = fc_b[j];
        #pragma unroll 4
        for (int i = 0; i < NSPANS * 64; ++i)
            s += fcT[(size_t)i * 512 + j] * emb[i];           // j coalesced
        s = fmaxf(s, 0.f);
        hbuf[j] = (s - bn2_m[j]) * rsqrtf(bn2_v[j] + 1e-5f) * bn2_g[j] + bn2_b[j];
    }
    __syncthreads();

    if (wv < 3) {
        const float* lw = last_w + wv * (HIDDEN + 17);
        float s = 0.f;
        for (int i = lane; i < HIDDEN + 17; i += 64) {
            float f;
            if (i < HIDDEN)          f = hbuf[i];
            else if (i < HIDDEN + 3) f = in_urls[b * 3 + (i - HIDDEN)];
            else                     f = other[b * 14 + (i - HIDDEN - 3)];
            s += lw[i] * f;
        }
        #pragma unroll
        for (int off = 32; off >= 1; off >>= 1) s += __shfl_xor(s, off);
        if (lane == 0) out[b * 3 + wv] = s + last_b[wv];
    }
}

extern "C" void kernel_launch(void* const* d_in, const int* in_sizes, int n_in,
                              void* d_out, int out_size, void* d_ws, size_t ws_size,
                              hipStream_t stream) {
    const float* bert    = (const float*)d_in[0];
    const int*   offs    = (const int*)d_in[1];
    const float* in_urls = (const float*)d_in[2];
    const float* other   = (const float*)d_in[3];
    const float* conv_w  = (const float*)d_in[4];
    const float* conv_b  = (const float*)d_in[5];
    const float* att_w   = (const float*)d_in[6];
    // att_b cancels in the softmax shift — unused.
    const float* bn1_g   = (const float*)d_in[8];
    const float* bn1_b   = (const float*)d_in[9];
    const float* bn1_m   = (const float*)d_in[10];
    const float* bn1_v   = (const float*)d_in[11];
    const float* fc_w    = (const float*)d_in[12];
    const float* fc_b    = (const float*)d_in[13];
    const float* bn2_g   = (const float*)d_in[14];
    const float* bn2_b   = (const float*)d_in[15];
    const float* bn2_m   = (const float*)d_in[16];
    const float* bn2_v   = (const float*)d_in[17];
    const float* last_w  = (const float*)d_in[18];
    const float* last_b  = (const float*)d_in[19];

    float* u    = (float*)d_ws;
    float* Wt2  = (float*)((char*)d_ws + 12288);
    float* fcT  = (float*)((char*)d_ws + 798720);
    float* d0   = (float*)((char*)d_ws + 1191936);
    float* d1   = (float*)((char*)d_ws + 1454080);
    float* d2   = (float*)((char*)d_ws + 1716224);
    float* Zv   = (float*)((char*)d_ws + 1978368);
    float* C    = (float*)((char*)d_ws + 1979904);
    float* part = (float*)((char*)d_ws + 5125632);

    hipLaunchKernelGGL(prep_kernel, dim3(96), dim3(256), 0, stream,
                       conv_w, att_w, fc_w, u, Wt2, fcT);
    hipLaunchKernelGGL(dots_kernel, dim3(DG), dim3(256), 0, stream,
                       bert, u, d0, d1, d2);
    hipLaunchKernelGGL(coef_kernel, dim3(B_), dim3(256), 0, stream,
                       d0, d1, d2, offs, C, Zv);
    hipLaunchKernelGGL(span_acc_kernel, dim3(B_ * 8), dim3(256), 0, stream,
                       bert, C, part);
    hipLaunchKernelGGL(head_kernel, dim3(B_), dim3(256), 0, stream,
                       part, Zv, Wt2, conv_b, fcT, in_urls, other,
                       bn1_g, bn1_b, bn1_m, bn1_v, fc_b,
                       bn2_g, bn2_b, bn2_m, bn2_v, last_w, last_b,
                       (float*)d_out);
}